// Round 7
// baseline (1069.256 us; speedup 1.0000x reference)
//
#include <hip/hip_runtime.h>
#include <hip/hip_bf16.h>
#include <math.h>

typedef __attribute__((ext_vector_type(8))) short short8;
typedef __attribute__((ext_vector_type(4))) float f32x4;
typedef unsigned short ushortT;

// ---------- helpers ----------
__device__ __forceinline__ unsigned short f2b(float f) {
  union { float f; unsigned u; } v; v.f = f;
  return (unsigned short)((v.u + 0x7FFFu + ((v.u >> 16) & 1u)) >> 16);
}
__device__ __forceinline__ float b2f(unsigned short h) {
  union { unsigned u; float f; } v; v.u = ((unsigned)h) << 16;
  return v.f;
}
__device__ __forceinline__ float gelu_f(float x) {
  return 0.5f * x * (1.0f + tanhf(0.7978845608028654f * (x + 0.044715f * x * x * x)));
}

// async 16B global -> LDS DMA. LDS dest = wave-uniform base + lane*16.
__device__ __forceinline__ void async16(ushortT* lds, const ushortT* g) {
  __builtin_amdgcn_global_load_lds(
      (const __attribute__((address_space(1))) void*)g,
      (__attribute__((address_space(3))) void*)lds, 16, 0, 0);
}

// ---------- GEMM-256x128: 8 waves, BK=32, minimum-2-phase schedule ----------
// Structure per K-tile (the verified T3-minimum recipe): issue STAGE(t+1) FIRST,
// then ds_read tile t + MFMA (loads fly under compute), then ONE vmcnt(0)+barrier.
// WAR: iter t's LDS reads drain (compiler lgkmcnt before MFMA) before end-of-t
// barrier; iter t+1's stage writes to the other buffer are issued after it.
// RAW: tile t+1's loads waited by end-of-t vmcnt(0) + barrier before reads.
// Same XOR swizzle involution as gemm_f (slot ^= (row>>1)&3, pre-swizzled
// global source + swizzled ds_read; LDS dest linear per rule 21).
// REQUIRES: M mult 256, N mult 128, K mult 32 >= 64.
template<int EMODE>
__global__ __launch_bounds__(512, 4)
void gemm8b(const ushortT* __restrict__ A, const ushortT* __restrict__ Bt,
            const ushortT* __restrict__ A2, const ushortT* __restrict__ Bt2,
            ushortT* __restrict__ C, ushortT* __restrict__ C2,
            const float* __restrict__ bias, const float* __restrict__ bias2,
            int zsplit, int bmode, float scale, long bstride,
            int K, int lda, int ldb, int ldc,
            long sA, long sB, long sC, const float2* __restrict__ tab)
{
  __shared__ ushortT lds[2][12288];   // per buf: A 256x32 @0 (8192), B 128x32 @8192 (4096)
  // --- XCD-aware bijective block remap ---
  const int gx = gridDim.x, gy = gridDim.y;
  int flat = blockIdx.x + gx * (blockIdx.y + gy * blockIdx.z);
  const int nwg = gx * gy * gridDim.z;
  if ((nwg & 7) == 0) { const int per = nwg >> 3; flat = (flat & 7) * per + (flat >> 3); }
  const int gxy = gx * gy;
  const int z = flat / gxy;
  const int rem = flat - z * gxy;
  const int bm = (rem / gx) * 256, bn = (rem % gx) * 128;

  int zz = z;
  const ushortT* Ap = A; const ushortT* Bp = Bt; const float* bp = bias;
  if (z >= zsplit) { Ap = A2; Bp = Bt2; bp = bias2; zz = z - zsplit; }
  Ap += (long)zz * sA;
  Bp += (long)zz * sB;
  const long coff = (long)z * sC;
  const int tid = threadIdx.x, wave = tid >> 6, lane = tid & 63;
  const int wm = (wave >> 1) << 6;   // 0,64,128,192 (4 M-groups)
  const int wn = (wave & 1) << 6;    // 0,64        (2 N-groups)
  const int l15 = lane & 15, quad = lane >> 4;
  const int x0 = (l15 >> 1) & 3;

  // staging addresses: A 2 sweeps of 128 rows, B 1 sweep of 128 rows
  const ushortT* gA[2]; const ushortT* gBp; int la[2]; int lb;
#pragma unroll
  for (int s = 0; s < 2; ++s) {
    int r = s * 128 + (tid >> 2);
    int sw = (((tid & 3) ^ ((r >> 1) & 3)) << 3);
    gA[s] = Ap + (long)(bm + r) * lda + sw;
    la[s] = s * 4096 + tid * 8;
  }
  {
    int r = tid >> 2;
    int sw = (((tid & 3) ^ ((r >> 1) & 3)) << 3);
    gBp = Bp + (long)(bn + r) * ldb + sw;
    lb = 8192 + tid * 8;
  }

  f32x4 acc[4][4];
#pragma unroll
  for (int i = 0; i < 4; ++i)
#pragma unroll
    for (int j = 0; j < 4; ++j) acc[i][j] = (f32x4){0.f, 0.f, 0.f, 0.f};

  const int nk = K >> 5;   // >= 2

  // prologue: stage tile 0
  async16(&lds[0][la[0]], gA[0]);
  async16(&lds[0][la[1]], gA[1]);
  async16(&lds[0][lb], gBp);
  asm volatile("s_waitcnt vmcnt(0)" ::: "memory");
  __builtin_amdgcn_s_barrier();

  int cur = 0;
  for (int t = 0; t < nk; ++t) {
    if (t + 1 < nk) {       // STAGE FIRST: latency hides under ds_read+MFMA below
      int k0 = (t + 1) << 5;
      async16(&lds[cur ^ 1][la[0]], gA[0] + k0);
      async16(&lds[cur ^ 1][la[1]], gA[1] + k0);
      async16(&lds[cur ^ 1][lb], gBp + k0);
    }
    short8 aF[4];
#pragma unroll
    for (int i = 0; i < 4; ++i)
      aF[i] = *(const short8*)&lds[cur][((wm + i * 16 + l15) << 5) + ((quad ^ x0) << 3)];
#pragma unroll
    for (int j = 0; j < 4; ++j) {
      short8 bF = *(const short8*)&lds[cur][8192 + ((wn + j * 16 + l15) << 5) + ((quad ^ x0) << 3)];
#pragma unroll
      for (int i = 0; i < 4; ++i)
        acc[i][j] = __builtin_amdgcn_mfma_f32_16x16x32_bf16(aF[i], bF, acc[i][j], 0, 0, 0);
    }
    asm volatile("s_waitcnt vmcnt(0)" ::: "memory");
    __builtin_amdgcn_s_barrier();
    cur ^= 1;
  }
  __syncthreads();

  // epilogue: two 128x128 half-passes through LDS C-tile
  ushortT* ct = &lds[0][0];
  const float* bz = bp + (long)zz * bstride;
  const int lr = wm & 127;
  const int myh = wm >> 7;
#pragma unroll
  for (int h = 0; h < 2; ++h) {
    if (myh == h) {
#pragma unroll
      for (int j = 0; j < 4; ++j) {
        int tcol = wn + j * 16 + l15;
        float cbv = (bmode == 1) ? bz[bn + tcol] : 0.0f;
#pragma unroll
        for (int i = 0; i < 4; ++i) {
          int r0l = lr + i * 16 + (quad << 2);
#pragma unroll
          for (int r = 0; r < 4; ++r) {
            int rowl = r0l + r;
            float bv = (bmode == 2) ? bz[bm + h * 128 + rowl] : cbv;
            float v = acc[i][j][r] * scale + bv;
            if (EMODE == 1) v = gelu_f(v);
            ct[(rowl << 7) + tcol] = f2b(v);
          }
        }
      }
    }
    __syncthreads();
    if (EMODE == 2) {
      const bool isq = (bn < 512);
      ushortT* dbase = isq ? C : C2;
      const int cbase = isq ? bn : bn - 512;
#pragma unroll
      for (int it = 0; it < 4; ++it) {
        int trow = it * 32 + (tid >> 4);
        int tcol = (tid & 15) << 3;
        uint4 u = *(const uint4*)&ct[(trow << 7) + tcol];
        int grow = bm + h * 128 + trow;
        int pos = grow & 1023;
        int pair0 = (cbase + tcol) >> 1;
        const float2* tp = &tab[(pos << 8) + pair0];
        unsigned w[4] = {u.x, u.y, u.z, u.w};
        uint4 o; unsigned* op = (unsigned*)&o;
#pragma unroll
        for (int p = 0; p < 4; ++p) {
          float2 sc = tp[p];
          float xx1 = b2f((ushortT)(w[p] & 0xFFFFu));
          float xx2 = b2f((ushortT)(w[p] >> 16));
          float o1 = xx1 * sc.y - xx2 * sc.x;
          float o2 = xx1 * sc.x + xx2 * sc.y;
          op[p] = (unsigned)f2b(o1) | ((unsigned)f2b(o2) << 16);
        }
        *(uint4*)&dbase[coff + (long)grow * 512 + cbase + tcol] = o;
      }
    } else {
#pragma unroll
      for (int it = 0; it < 4; ++it) {
        int trow = it * 32 + (tid >> 4);
        int tcol = (tid & 15) << 3;
        *(uint4*)&C[coff + (long)(bm + h * 128 + trow) * ldc + bn + tcol] =
            *(const uint4*)&ct[(trow << 7) + tcol];
      }
    }
    __syncthreads();
  }
}

// ---------- GEMM-128 (proven): used for shapes that don't fit gemm8b ----------
template<int EMODE>
__global__ __launch_bounds__(256, 3)
void gemm_f(const ushortT* __restrict__ A, const ushortT* __restrict__ Bt,
            const ushortT* __restrict__ A2, const ushortT* __restrict__ Bt2,
            ushortT* __restrict__ C, ushortT* __restrict__ C2,
            const float* __restrict__ bias, const float* __restrict__ bias2,
            int zsplit, int bmode, float scale, long bstride,
            int K, int lda, int ldb, int ldc,
            long sA, long sB, long sC, const float2* __restrict__ tab)
{
  __shared__ ushortT lds[3][2][128 * 32];
  const int gx = gridDim.x, gy = gridDim.y;
  int flat = blockIdx.x + gx * (blockIdx.y + gy * blockIdx.z);
  const int nwg = gx * gy * gridDim.z;
  if ((nwg & 7) == 0) {
    const int per = nwg >> 3;
    flat = (flat & 7) * per + (flat >> 3);
  }
  const int gxy = gx * gy;
  const int z = flat / gxy;
  const int rem = flat - z * gxy;
  const int bm = (rem / gx) * 128, bn = (rem % gx) * 128;

  int zz = z;
  const ushortT* Ap = A; const ushortT* Bp = Bt; const float* bp = bias;
  if (z >= zsplit) { Ap = A2; Bp = Bt2; bp = bias2; zz = z - zsplit; }
  Ap += (long)zz * sA;
  Bp += (long)zz * sB;
  const long coff = (long)z * sC;
  const int tid = threadIdx.x, wave = tid >> 6, lane = tid & 63;
  const int wm = (wave >> 1) << 6, wn = (wave & 1) << 6;
  const int l15 = lane & 15, quad = lane >> 4;

  const ushortT* gA[2]; const ushortT* gB[2];
  int lchunk[2];
#pragma unroll
  for (int q = 0; q < 2; ++q) {
    int r = 32 * wave + 16 * q + (lane >> 2);
    int sw = (((lane & 3) ^ ((r >> 1) & 3)) << 3);
    gA[q] = Ap + (long)(bm + r) * lda + sw;
    gB[q] = Bp + (long)(bn + r) * ldb + sw;
    lchunk[q] = (wave * 2 + q) * 512;
  }

  f32x4 acc[4][4];
#pragma unroll
  for (int i = 0; i < 4; ++i)
#pragma unroll
    for (int j = 0; j < 4; ++j) acc[i][j] = (f32x4){0.f, 0.f, 0.f, 0.f};

  const int x0 = (l15 >> 1) & 3;
  const int nk = K >> 5;

#pragma unroll
  for (int q = 0; q < 2; ++q) {
    async16(&lds[0][0][lchunk[q]], gA[q]);
    async16(&lds[0][1][lchunk[q]], gB[q]);
  }
#pragma unroll
  for (int q = 0; q < 2; ++q) {
    async16(&lds[1][0][lchunk[q]], gA[q] + 32);
    async16(&lds[1][1][lchunk[q]], gB[q] + 32);
  }

  int rb_ = 0, sb_ = 2;
  for (int k = 0; k < nk; ++k) {
    if (k + 2 < nk) {
      int k0 = (k + 2) << 5;
#pragma unroll
      for (int q = 0; q < 2; ++q) {
        async16(&lds[sb_][0][lchunk[q]], gA[q] + k0);
        async16(&lds[sb_][1][lchunk[q]], gB[q] + k0);
      }
    }
    if (k + 2 < nk)      asm volatile("s_waitcnt vmcnt(8)" ::: "memory");
    else if (k + 1 < nk) asm volatile("s_waitcnt vmcnt(4)" ::: "memory");
    else                 asm volatile("s_waitcnt vmcnt(0)" ::: "memory");
    __builtin_amdgcn_s_barrier();
    asm volatile("" ::: "memory");

    short8 aF[4], bF[4];
#pragma unroll
    for (int t = 0; t < 4; ++t) {
      int ra = (wm + t * 16 + l15) << 5;
      aF[t] = *(const short8*)&lds[rb_][0][ra + ((quad ^ x0) << 3)];
      int rbo = (wn + t * 16 + l15) << 5;
      bF[t] = *(const short8*)&lds[rb_][1][rbo + ((quad ^ x0) << 3)];
    }
#pragma unroll
    for (int i = 0; i < 4; ++i)
#pragma unroll
      for (int j = 0; j < 4; ++j)
        acc[i][j] = __builtin_amdgcn_mfma_f32_16x16x32_bf16(aF[i], bF[j], acc[i][j], 0, 0, 0);

    asm volatile("s_waitcnt lgkmcnt(0)" ::: "memory");
    __builtin_amdgcn_s_barrier();
    asm volatile("" ::: "memory");
    rb_ = (rb_ == 2) ? 0 : rb_ + 1;
    sb_ = (sb_ == 2) ? 0 : sb_ + 1;
  }
  __syncthreads();

  ushortT* ct = &lds[0][0][0];
  const float* bz = bp + (long)zz * bstride;
#pragma unroll
  for (int j = 0; j < 4; ++j) {
    int tcol = wn + j * 16 + l15;
    float cbv = (bmode == 1) ? bz[bn + tcol] : 0.0f;
#pragma unroll
    for (int i = 0; i < 4; ++i) {
      int row0 = wm + i * 16 + (quad << 2);
#pragma unroll
      for (int r = 0; r < 4; ++r) {
        int row = row0 + r;
        float bv = (bmode == 2) ? bz[bm + row] : cbv;
        float v = acc[i][j][r] * scale + bv;
        if (EMODE == 1) v = gelu_f(v);
        ct[(row << 7) + tcol] = f2b(v);
      }
    }
  }
  __syncthreads();

  if (EMODE == 2) {
    const bool isq = (bn < 512);
    ushortT* dbase = isq ? C : C2;
    const int cbase = isq ? bn : bn - 512;
#pragma unroll
    for (int it = 0; it < 8; ++it) {
      int trow = it * 16 + (tid >> 4);
      int tcol = (tid & 15) << 3;
      uint4 u = *(const uint4*)&ct[(trow << 7) + tcol];
      int grow = bm + trow;
      int pos = grow & 1023;
      int pair0 = (cbase + tcol) >> 1;
      const float2* tp = &tab[(pos << 8) + pair0];
      unsigned w[4] = {u.x, u.y, u.z, u.w};
      uint4 o;
      unsigned* op = (unsigned*)&o;
#pragma unroll
      for (int p = 0; p < 4; ++p) {
        float2 sc = tp[p];
        float x1 = b2f((ushortT)(w[p] & 0xFFFFu));
        float x2 = b2f((ushortT)(w[p] >> 16));
        float o1 = x1 * sc.y - x2 * sc.x;
        float o2 = x1 * sc.x + x2 * sc.y;
        op[p] = (unsigned)f2b(o1) | ((unsigned)f2b(o2) << 16);
      }
      *(uint4*)&dbase[coff + (long)grow * 512 + cbase + tcol] = o;
    }
  } else {
#pragma unroll
    for (int it = 0; it < 8; ++it) {
      int trow = it * 16 + (tid >> 4);
      int tcol = (tid & 15) << 3;
      *(uint4*)&C[coff + (long)(bm + trow) * ldc + bn + tcol] =
          *(const uint4*)&ct[(trow << 7) + tcol];
    }
  }
}

// ---------- batched tiled transpose (z,R,C)->(z,C,R) bf16->bf16, optional gather ----------
__global__ void btrans(const ushortT* __restrict__ in, ushortT* __restrict__ out,
                       int R, int C, long ibs, const int* __restrict__ gather) {
  __shared__ float tile[32][33];
  int z = blockIdx.z;
  long ib = (long)(gather ? gather[z] : z) * ibs;
  long ob = (long)z * (long)R * C;
  int c0 = blockIdx.x << 5, r0 = blockIdx.y << 5;
  int tx = threadIdx.x, ty = threadIdx.y;
#pragma unroll
  for (int dy = 0; dy < 32; dy += 8)
    tile[ty + dy][tx] = b2f(in[ib + (long)(r0 + ty + dy) * C + c0 + tx]);
  __syncthreads();
#pragma unroll
  for (int dy = 0; dy < 32; dy += 8)
    out[ob + (long)(c0 + ty + dy) * R + r0 + tx] = f2b(tile[tx][ty + dy]);
}

// ---------- all 26 weight transposes in one dispatch: f32 (512,512) -> bf16 W^T ----------
struct WSrc { const float* p[8]; int c[8]; };
__global__ void wtrans_all(WSrc ws, ushortT* __restrict__ out) {
  __shared__ float tile[32][33];
  int z = blockIdx.z;
  int g = 0, base = 0;
  while (z - base >= ws.c[g]) { base += ws.c[g]; ++g; }
  const float* src = ws.p[g] + (size_t)(z - base) * 262144;
  ushortT* dst = out + (size_t)z * 262144;
  int c0 = blockIdx.x << 5, r0 = blockIdx.y << 5;
  int tx = threadIdx.x, ty = threadIdx.y;
#pragma unroll
  for (int dy = 0; dy < 32; dy += 8)
    tile[ty + dy][tx] = src[(long)(r0 + ty + dy) * 512 + c0 + tx];
  __syncthreads();
#pragma unroll
  for (int dy = 0; dy < 32; dy += 8)
    dst[(long)(c0 + ty + dy) * 512 + r0 + tx] = f2b(tile[tx][ty + dy]);
}

// ---------- fused setup: softmax biases, rope table, f32->bf16 convs, zero vec ----------
__device__ __forceinline__ void conv4(const float4* in, uint2* out, long i) {
  float4 v = in[i];
  uint2 r;
  r.x = (unsigned)f2b(v.x) | ((unsigned)f2b(v.y) << 16);
  r.y = (unsigned)f2b(v.z) | ((unsigned)f2b(v.w) << 16);
  out[i] = r;
}
__global__ __launch_bounds__(256)
void setup_k(const float* __restrict__ rpw, const float* __restrict__ rpr,
             const float* __restrict__ questions, const float* __restrict__ raw,
             const float* __restrict__ pd,
             float* __restrict__ pbw, float* __restrict__ pbr, float2* __restrict__ tab,
             uint2* __restrict__ qsb, uint2* __restrict__ rab, uint2* __restrict__ pdb,
             float* __restrict__ zb) {
  int b = blockIdx.x, t = threadIdx.x;
  if (b < 32) { int i = b * 256 + t; float v = rpw[i]; pbw[i] = __logf(v); return; }
  b -= 32;
  if (b < 64) { int i = b * 256 + t; float v = rpr[i]; pbr[i] = __logf(v) - log1pf(-v); return; }
  b -= 64;
  if (b < 1024) {
    float inv = __expf(-(float)t * 0.035977892078032f);
    float s, c;
    sincosf((float)b * inv, &s, &c);
    tab[(b << 8) + t] = make_float2(s, c);
    return;
  }
  b -= 1024;
  if (b < 32) { conv4((const float4*)questions, qsb, (long)b * 256 + t); return; }
  b -= 32;
  if (b < 4096) { conv4((const float4*)raw, rab, (long)b * 256 + t); return; }
  b -= 4096;
  if (b < 8192) { conv4((const float4*)pd, pdb, (long)b * 256 + t); return; }
  b -= 8192;
  zb[b * 256 + t] = 0.0f;
}

// ---------- in-place softmax, L=1024, WAVE-PER-ROW (4 rows/block, 16 elem/lane) ----------
__global__ __launch_bounds__(256)
void softmax1024(ushortT* __restrict__ x) {
  int row = blockIdx.x * 4 + (threadIdx.x >> 6), lane = threadIdx.x & 63;
  ushortT* xr = x + (long)row * 1024;
  uint4 u0 = ((const uint4*)xr)[lane * 2];
  uint4 u1 = ((const uint4*)xr)[lane * 2 + 1];
  unsigned w[8] = {u0.x, u0.y, u0.z, u0.w, u1.x, u1.y, u1.z, u1.w};
  float t[16];
#pragma unroll
  for (int i = 0; i < 8; ++i) {
    t[2 * i]     = b2f((ushortT)(w[i] & 0xFFFFu));
    t[2 * i + 1] = b2f((ushortT)(w[i] >> 16));
  }
  float m = t[0];
#pragma unroll
  for (int i = 1; i < 16; ++i) m = fmaxf(m, t[i]);
  for (int o = 32; o; o >>= 1) m = fmaxf(m, __shfl_xor(m, o));
  float s = 0.f;
#pragma unroll
  for (int i = 0; i < 16; ++i) { t[i] = __expf(t[i] - m); s += t[i]; }
  for (int o = 32; o; o >>= 1) s += __shfl_xor(s, o);
  float inv = 1.0f / s;
#pragma unroll
  for (int i = 0; i < 8; ++i)
    w[i] = (unsigned)f2b(t[2 * i] * inv) | ((unsigned)f2b(t[2 * i + 1] * inv) << 16);
  uint4 o0; o0.x = w[0]; o0.y = w[1]; o0.z = w[2]; o0.w = w[3];
  uint4 o1; o1.x = w[4]; o1.y = w[5]; o1.z = w[6]; o1.w = w[7];
  ((uint4*)xr)[lane * 2]     = o0;
  ((uint4*)xr)[lane * 2 + 1] = o1;
}

// ---------- in-place softmax, L=64 (one wave per row; scale pre-folded) ----------
__global__ __launch_bounds__(256)
void softmax64(ushortT* __restrict__ x, int ldr) {
  int row = blockIdx.x * 4 + (threadIdx.x >> 6), lane = threadIdx.x & 63;
  ushortT* xr = x + (long)row * ldr;
  float t = b2f(xr[lane]);
  float m = t;
  for (int o = 32; o; o >>= 1) m = fmaxf(m, __shfl_xor(m, o));
  float e = __expf(t - m), s = e;
  for (int o = 32; o; o >>= 1) s += __shfl_xor(s, o);
  xr[lane] = f2b(e / s);
}

// ---------- fused residual + LayerNorm, WAVE-PER-ROW (4 rows/block, 8 elem/lane) ----------
__global__ __launch_bounds__(256)
void ln_k(const ushortT* __restrict__ src, const ushortT* __restrict__ res,
          const float* __restrict__ gamma, const float* __restrict__ beta,
          const float* __restrict__ gamma2, const float* __restrict__ beta2,
          int rsplit, ushortT* __restrict__ dst) {
  int row = blockIdx.x * 4 + (threadIdx.x >> 6), lane = threadIdx.x & 63;
  const float* gp = gamma; const float* bp = beta;
  if (row >= rsplit) { gp = gamma2; bp = beta2; }
  long off = (long)row * 512 + lane * 8;
  short8 sv = *(const short8*)&src[off];
  short8 rv = *(const short8*)&res[off];
  float a[8]; float s = 0.f, q = 0.f;
#pragma unroll
  for (int j = 0; j < 8; ++j) {
    a[j] = b2f((ushortT)sv[j]) + b2f((ushortT)rv[j]);
    s += a[j]; q += a[j] * a[j];
  }
  for (int o = 32; o; o >>= 1) { s += __shfl_xor(s, o); q += __shfl_xor(q, o); }
  float mean = s * (1.0f / 512.0f);
  float var = q * (1.0f / 512.0f) - mean * mean;
  float rstd = rsqrtf(fmaxf(var, 0.f) + 1e-5f);
  unsigned w[4];
#pragma unroll
  for (int j = 0; j < 4; ++j) {
    float v0 = (a[2 * j]     - mean) * rstd * gp[lane * 8 + 2 * j]     + bp[lane * 8 + 2 * j];
    float v1 = (a[2 * j + 1] - mean) * rstd * gp[lane * 8 + 2 * j + 1] + bp[lane * 8 + 2 * j + 1];
    w[j] = (unsigned)f2b(v0) | ((unsigned)f2b(v1) << 16);
  }
  uint4 o; o.x = w[0]; o.y = w[1]; o.z = w[2]; o.w = w[3];
  *(uint4*)&dst[off] = o;
}

// ---------- v = raw * sigmoid(fi @ W_ig + b_ig), WAVE-PER-ROW ----------
__global__ __launch_bounds__(256)
void gatev_k(const ushortT* __restrict__ fi, const float* __restrict__ raw,
             const float* __restrict__ wig, const float* __restrict__ big,
             ushortT* __restrict__ vout) {
  int row = blockIdx.x * 4 + (threadIdx.x >> 6), lane = threadIdx.x & 63;
  long off = (long)row * 512 + lane * 8;
  short8 fv = *(const short8*)&fi[off];
  float d = 0.f;
#pragma unroll
  for (int j = 0; j < 8; ++j) d += b2f((ushortT)fv[j]) * wig[lane * 8 + j];
  for (int o = 32; o; o >>= 1) d += __shfl_xor(d, o);
  float g = 1.0f / (1.0f + __expf(-(d + big[0])));
  float4 r0 = *(const float4*)&raw[off];
  float4 r1 = *(const float4*)&raw[off + 4];
  unsigned w[4];
  w[0] = (unsigned)f2b(r0.x * g) | ((unsigned)f2b(r0.y * g) << 16);
  w[1] = (unsigned)f2b(r0.z * g) | ((unsigned)f2b(r0.w * g) << 16);
  w[2] = (unsigned)f2b(r1.x * g) | ((unsigned)f2b(r1.y * g) << 16);
  w[3] = (unsigned)f2b(r1.z * g) | ((unsigned)f2b(r1.w * g) << 16);
  uint4 o; o.x = w[0]; o.y = w[1]; o.z = w[2]; o.w = w[3];
  *(uint4*)&vout[off] = o;
}

// ---------- final gating + output write (f32 out), WAVE-PER-ROW ----------
__global__ __launch_bounds__(256)
void final_k(const ushortT* __restrict__ fu, const ushortT* __restrict__ A2,
             const float* __restrict__ pd, const float* __restrict__ wu1,
             const float* __restrict__ wu2, const float* __restrict__ bu1,
             const float* __restrict__ bu2, const float* __restrict__ b1p,
             float* __restrict__ outx, float* __restrict__ outg) {
  int row = blockIdx.x * 4 + (threadIdx.x >> 6), lane = threadIdx.x & 63;
  long off = (long)row * 512 + lane * 8;
  short8 fv = *(const short8*)&fu[off];
  short8 av = *(const short8*)&A2[off];
  float a2[8]; float d1 = 0.f, d2 = 0.f;
#pragma unroll
  for (int j = 0; j < 8; ++j) {
    a2[j] = b2f((ushortT)av[j]);
    d1 += b2f((ushortT)fv[j]) * wu1[lane * 8 + j];
    d2 += a2[j] * wu2[lane * 8 + j];
  }
  for (int o = 32; o; o >>= 1) { d1 += __shfl_xor(d1, o); d2 += __shfl_xor(d2, o); }
  float g = 1.0f / (1.0f + __expf(-(d1 + d2 + bu1[0] + bu2[0] + b1p[0] - 4.0f)));
  float4 p0 = *(const float4*)&pd[off];
  float4 p1 = *(const float4*)&pd[off + 4];
  float4 o0, o1;
  o0.x = p0.x * (1.0f - g) + a2[0] * g;
  o0.y = p0.y * (1.0f - g) + a2[1] * g;
  o0.z = p0.z * (1.0f - g) + a2[2] * g;
  o0.w = p0.w * (1.0f - g) + a2[3] * g;
  o1.x = p1.x * (1.0f - g) + a2[4] * g;
  o1.y = p1.y * (1.0f - g) + a2[5] * g;
  o1.z = p1.z * (1.0f - g) + a2[6] * g;
  o1.w = p1.w * (1.0f - g) + a2[7] * g;
  *(float4*)&outx[off]     = o0;
  *(float4*)&outx[off + 4] = o1;
  if (lane == 0) outg[row] = g;
}

// ================= host orchestration =================
extern "C" void kernel_launch(void* const* d_in, const int* in_sizes, int n_in,
                              void* d_out, int out_size, void* d_ws, size_t ws_size,
                              hipStream_t stream)
{
  const float* raw_emb = (const float*)d_in[0];
  const float* rpw     = (const float*)d_in[1];
  const float* post_dec= (const float*)d_in[2];
  const float* rpr     = (const float*)d_in[3];
  const float* questions=(const float*)d_in[4];
  const float* W_k  = (const float*)d_in[5];
  const float* W_ig = (const float*)d_in[6];
  const float* b_ig = (const float*)d_in[7];
  const float* W_u1 = (const float*)d_in[8];
  const float* b_u1 = (const float*)d_in[9];
  const float* W_u2 = (const float*)d_in[10];
  const float* b_u2 = (const float*)d_in[11];
  const float* b1   = (const float*)d_in[12];
  const float* W_ok = (const float*)d_in[13];
  const float* b_ok = (const float*)d_in[14];
  const float* ew_qkv = (const float*)d_in[15];
  const float* ew_bqkv= (const float*)d_in[16];
  const float* ew_wo  = (const float*)d_in[17];
  const float* ew_bo  = (const float*)d_in[18];
  const float* ew_ln  = (const float*)d_in[19];
  const float* ew_wff = (const float*)d_in[20];
  const float* ew_bff = (const float*)d_in[21];
  const float* er_qkv = (const float*)d_in[22];
  const float* er_bqkv= (const float*)d_in[23];
  const float* er_wo  = (const float*)d_in[24];
  const float* er_bo  = (const float*)d_in[25];
  const float* er_ln  = (const float*)d_in[26];
  const float* er_wff = (const float*)d_in[27];
  const float* er_bff = (const float*)d_in[28];
  const int* lookup   = (const int*)d_in[29];

  const size_t MAT = 512ull * 512ull;
  const long SD = 1024l * 512;
  const long SZ = 8192l * 512;
  const int BIGZ = 1 << 28;
  char* wsb = (char*)d_ws;
  size_t off = 0;
  auto alloc = [&](size_t b) { char* p = wsb + off; off = (off + b + 255) & ~(size_t)255; return p; };

  ushortT* WT  = (ushortT*)alloc(26 * MAT * 2);
  ushortT* RAB = (ushortT*)alloc(8192ull * 512 * 2);
  ushortT* PDB = (ushortT*)alloc(16384ull * 512 * 2);
  ushortT* XC  = (ushortT*)alloc(24576ull * 512 * 2);
  ushortT* B1  = (ushortT*)alloc(24576ull * 512 * 2);
  ushortT* SC  = (ushortT*)alloc(24ull * 1024 * 1024 * 2);
  ushortT* QB  = (ushortT*)alloc(24576ull * 512 * 2);
  ushortT* KB  = (ushortT*)alloc(24576ull * 512 * 2);
  ushortT* VT  = (ushortT*)alloc(24ull * 512 * 1024 * 2);
  ushortT* KD2 = (ushortT*)alloc(24576ull * 512 * 2);
  ushortT* QSB = (ushortT*)alloc(128ull * 512 * 2);
  ushortT* SC2 = (ushortT*)alloc(16384ull * 128 * 2);
  ushortT* A1S = (ushortT*)alloc(8ull * 128 * 512 * 2);
  ushortT* SAT = (ushortT*)alloc(16ull * 512 * 64 * 2);
  float*   PBW = (float*)alloc(8192 * 4);
  float*   PBR = (float*)alloc(16384 * 4);
  float2*  TAB = (float2*)alloc(1024 * 256 * 8);
  float*   ZB  = (float*)alloc(512 * 4);

  // route big shapes (M%256==0, N%128==0, grid >=192 blocks) to gemm8b
  auto gemm = [&](int emode, const ushortT* A, const ushortT* Bt,
                  const ushortT* A2p, const ushortT* Bt2p,
                  ushortT* C, ushortT* C2,
                  const float* bias, const float* bias2, int zsplit,
                  int bmode, float scale, long bstride,
                  int M, int N, int K, int lda, int ldb, int ldc,
                  int Z, long sA, long sB, long sC) {
    bool big = (M % 256 == 0) && (N % 128 == 0) && ((M / 256) * (N / 128) * Z >= 192);
    if (big) {
      dim3 g(N / 128, M / 256, Z);
      if (emode == 0)
        gemm8b<0><<<g, dim3(512), 0, stream>>>(A, Bt, A2p, Bt2p, C, nullptr, bias, bias2,
                                               zsplit, bmode, scale, bstride,
                                               K, lda, ldb, ldc, sA, sB, sC, TAB);
      else if (emode == 1)
        gemm8b<1><<<g, dim3(512), 0, stream>>>(A, Bt, A2p, Bt2p, C, nullptr, bias, bias2,
                                               zsplit, bmode, scale, bstride,
                                               K, lda, ldb, ldc, sA, sB, sC, TAB);
      else
        gemm8b<2><<<g, dim3(512), 0, stream>>>(A, Bt, A2p, Bt2p, C, C2, bias, bias2,
                                               zsplit, bmode, scale, bstride,
                                               K, lda, ldb, ldc, sA, sB, sC, TAB);
    } else {
      dim3 g(N / 128, M / 128, Z);
      if (emode == 0)
        gemm_f<0><<<g, dim3(256), 0, stream>>>(A, Bt, A2p, Bt2p, C, nullptr, bias, bias2,
                                               zsplit, bmode, scale, bstride,
                                               K, lda, ldb, ldc, sA, sB, sC, TAB);
      else if (emode == 1)
        gemm_f<1><<<g, dim3(256), 0, stream>>>(A, Bt, A2p, Bt2p, C, nullptr, bias, bias2,
                                               zsplit, bmode, scale, bstride,
                                               K, lda, ldb, ldc, sA, sB, sC, TAB);
      else
        gemm_f<2><<<g, dim3(256), 0, stream>>>(A, Bt, A2p, Bt2p, C, C2, bias, bias2,
                                               zsplit, bmode, scale, bstride,
                                               K, lda, ldb, ldc, sA, sB, sC, TAB);
    }
  };

  const float isc512 = 0.044194173824159216f; // 1/sqrt(512)

  // 0. setup
  WSrc wsrc;
  wsrc.p[0] = W_k;    wsrc.c[0] = 1;
  wsrc.p[1] = W_ok;   wsrc.c[1] = 1;
  wsrc.p[2] = ew_qkv; wsrc.c[2] = 6;
  wsrc.p[3] = ew_wo;  wsrc.c[3] = 2;
  wsrc.p[4] = ew_wff; wsrc.c[4] = 4;
  wsrc.p[5] = er_qkv; wsrc.c[5] = 6;
  wsrc.p[6] = er_wo;  wsrc.c[6] = 2;
  wsrc.p[7] = er_wff; wsrc.c[7] = 4;
  wtrans_all<<<dim3(16, 16, 26), dim3(32, 8), 0, stream>>>(wsrc, WT);
  setup_k<<<13442, 256, 0, stream>>>(rpw, rpr, questions, raw_emb, post_dec,
                                     PBW, PBR, TAB, (uint2*)QSB, (uint2*)RAB, (uint2*)PDB, ZB);

  // 1. merged k_docs + k2
  gemm(0, RAB, WT + 0 * MAT, RAB + SZ, WT + 1 * MAT, KD2, nullptr,
       ZB, b_ok, 1, 1, 1.0f, 0,
       8192, 512, 512, 512, 512, 512, 3, SZ, 0, SZ);

  // 2. merged dual-encoder sweep
  for (int l = 0; l < 2; ++l) {
    const ushortT* xs = (l == 0) ? RAB : XC;
    const ushortT* WqkW = WT + (size_t)(2 + l * 3) * MAT;
    const ushortT* WqkR = WT + (size_t)(14 + l * 3) * MAT;
    const ushortT* WvW  = WT + (size_t)(4 + l * 3) * MAT;
    const ushortT* WvR  = WT + (size_t)(16 + l * 3) * MAT;
    const ushortT* WoW  = WT + (size_t)(8 + l) * MAT;
    const ushortT* WoR  = WT + (size_t)(20 + l) * MAT;
    const ushortT* Wf0W = WT + (size_t)(10 + l * 2) * MAT;
    const ushortT* Wf0R = WT + (size_t)(22 + l * 2) * MAT;
    const ushortT* Wf1W = WT + (size_t)(11 + l * 2) * MAT;
    const ushortT* Wf1R = WT + (size_t)(23 + l * 2) * MAT;

    gemm(2, xs, WqkW, xs + SZ, WqkR, QB, KB,
         ew_bqkv + (l * 3) * 512, er_bqkv + (l * 3) * 512, 1,
         1, 1.0f, 0,
         8192, 1024, 512, 512, 512, 512, 3, SZ, 0, SZ);
    gemm(0, WvW, xs, WvR, xs + 8 * SD, VT, nullptr,
         ew_bqkv + (l * 3 + 2) * 512, er_bqkv + (l * 3 + 2) * 512, 8,
         2, 1.0f, 0,
         512, 1024, 512, 512, 512, 1024, 24, 0, SD, SD);
    gemm(0, QB, KB, QB, KB, SC, nullptr,
         PBW, PBW, BIGZ, 1, isc512, 1024,
         1024, 1024, 512, 512, 512, 1024, 24, SD, SD, 1024l * 1024);
    softmax1024<<<6144, 256, 0, stream>>>(SC);
    gemm(0, SC, VT, SC, VT, QB, nullptr,
         nullptr, nullptr, BIGZ, 0, 1.0f, 0,
         1024, 512, 1024, 1024, 1024, 512, 24, 1024l * 1024, SD, SD);
    gemm(0, QB, WoW, QB + SZ, WoR, B1, nullptr,
         ew_bo + l * 512, er_bo + l * 512, 1, 1, 1.0f, 0,
         8192, 512, 512, 512, 512, 512, 3, SZ, 0, SZ);
    ln_k<<<6144, 256, 0, stream>>>(xs, B1,
         ew_ln + (l * 4 + 0) * 512, ew_ln + (l * 4 + 1) * 512,
         er_ln + (l * 4 + 0) * 512, er_ln + (l * 4 + 1) * 512, 8192, XC);
    gemm(1, XC, Wf0W, XC + SZ, Wf0R, KB, nullptr,
         ew_bff + (l * 2) * 512, er_bff + (l * 2) * 512, 1, 1, 1.0f, 0,
         8192, 512, 512, 512, 512, 512, 3, SZ, 0, SZ);
    gemm(0, KB, Wf1W, KB + SZ, Wf1R, B1, nullptr,
         ew_bff + (l * 2 + 1) * 512, er_bff + (l * 2 + 1) * 512, 1, 1, 1.0f, 0,
         8192, 512, 512, 512, 512, 512, 3, SZ, 0, SZ);
    ln_k<<<6144, 256, 0, stream>>>(XC, B1,
         ew_ln + (l * 4 + 2) * 512, ew_ln + (l * 4 + 3) * 512,
         er_ln + (l * 4 + 2) * 512, er_ln + (l * 4 + 3) * 512, 8192, XC);
  }

  // 3. v_gate, A1s
  gatev_k<<<2048, 256, 0, stream>>>(XC, raw_emb, W_ig, b_ig, B1);
  btrans<<<dim3(16, 32, 8), dim3(32, 8), 0, stream>>>(B1, VT, 1024, 512, SD, nullptr);
  gemm(0, QSB, KD2, QSB, KD2, SC2, nullptr,
       PBW, PBW, BIGZ, 1, isc512, 1024,
       128, 1024, 512, 512, 512, 1024, 8, 0, SD, 128l * 1024);
  softmax1024<<<256, 256, 0, stream>>>(SC2);
  gemm(0, SC2, VT, SC2, VT, A1S, nullptr,
       nullptr, nullptr, BIGZ, 0, 1.0f, 0,
       128, 512, 1024, 1024, 1024, 512, 8, 128l * 1024, SD, 128l * 512);

  // 4. a2, A2
  gemm(0, KD2 + SZ, QSB, KD2 + SZ, QSB, SC2, nullptr,
       nullptr, nullptr, BIGZ, 0, 0.125f, 0,
       16384, 128, 512, 512, 512, 128, 1, 0, 0, 0);
  softmax64<<<4096, 256, 0, stream>>>(SC2, 128);
  btrans<<<dim3(16, 2, 16), dim3(32, 8), 0, stream>>>(A1S, SAT, 64, 512, 128 * 512, lookup);
  gemm(0, SC2, SAT, SC2, SAT, QB, nullptr,
       nullptr, nullptr, BIGZ, 0, 1.0f, 0,
       1024, 512, 64, 128, 64, 512, 16, 1024l * 128, 512l * 64, SD);

  // 5. final gate + output
  float* outp = (float*)d_out;
  final_k<<<4096, 256, 0, stream>>>(XC + SZ, QB, post_dec, W_u1, W_u2, b_u1, b_u2, b1,
                                    outp, outp + 8388608);
}

// Round 8
// 798.650 us; speedup vs baseline: 1.3388x; 1.3388x over previous
//
#include <hip/hip_runtime.h>
#include <hip/hip_bf16.h>
#include <math.h>

typedef __attribute__((ext_vector_type(8))) short short8;
typedef __attribute__((ext_vector_type(4))) float f32x4;
typedef unsigned short ushortT;

// ---------- helpers ----------
__device__ __forceinline__ unsigned short f2b(float f) {
  union { float f; unsigned u; } v; v.f = f;
  return (unsigned short)((v.u + 0x7FFFu + ((v.u >> 16) & 1u)) >> 16);
}
__device__ __forceinline__ float b2f(unsigned short h) {
  union { unsigned u; float f; } v; v.u = ((unsigned)h) << 16;
  return v.f;
}
__device__ __forceinline__ float gelu_f(float x) {
  return 0.5f * x * (1.0f + tanhf(0.7978845608028654f * (x + 0.044715f * x * x * x)));
}

// async 16B global -> LDS DMA. LDS dest = wave-uniform base + lane*16.
__device__ __forceinline__ void async16(ushortT* lds, const ushortT* g) {
  __builtin_amdgcn_global_load_lds(
      (const __attribute__((address_space(1))) void*)g,
      (__attribute__((address_space(3))) void*)lds, 16, 0, 0);
}

// ---------- GEMM-128 (proven best): 128x128 tile, BK=32, triple-buffer depth-2,
// counted vmcnt (never 0 mid-loop), XOR-swizzle, XCD-bijective remap,
// LDS-staged coalesced C writes. EMODE: 0=plain, 1=gelu, 2=rope split.
// Group select via zsplit (A2/Bt2/bias2, zz = z - zsplit). ----------
template<int EMODE>
__global__ __launch_bounds__(256, 3)
void gemm_f(const ushortT* __restrict__ A, const ushortT* __restrict__ Bt,
            const ushortT* __restrict__ A2, const ushortT* __restrict__ Bt2,
            ushortT* __restrict__ C, ushortT* __restrict__ C2,
            const float* __restrict__ bias, const float* __restrict__ bias2,
            int zsplit, int bmode, float scale, long bstride,
            int K, int lda, int ldb, int ldc,
            long sA, long sB, long sC, const float2* __restrict__ tab)
{
  __shared__ ushortT lds[3][2][128 * 32];
  const int gx = gridDim.x, gy = gridDim.y;
  int flat = blockIdx.x + gx * (blockIdx.y + gy * blockIdx.z);
  const int nwg = gx * gy * gridDim.z;
  if ((nwg & 7) == 0) {
    const int per = nwg >> 3;
    flat = (flat & 7) * per + (flat >> 3);
  }
  const int gxy = gx * gy;
  const int z = flat / gxy;
  const int rem = flat - z * gxy;
  const int bm = (rem / gx) * 128, bn = (rem % gx) * 128;

  int zz = z;
  const ushortT* Ap = A; const ushortT* Bp = Bt; const float* bp = bias;
  if (z >= zsplit) { Ap = A2; Bp = Bt2; bp = bias2; zz = z - zsplit; }
  Ap += (long)zz * sA;
  Bp += (long)zz * sB;
  const long coff = (long)z * sC;
  const int tid = threadIdx.x, wave = tid >> 6, lane = tid & 63;
  const int wm = (wave >> 1) << 6, wn = (wave & 1) << 6;
  const int l15 = lane & 15, quad = lane >> 4;

  const ushortT* gA[2]; const ushortT* gB[2];
  int lchunk[2];
#pragma unroll
  for (int q = 0; q < 2; ++q) {
    int r = 32 * wave + 16 * q + (lane >> 2);
    int sw = (((lane & 3) ^ ((r >> 1) & 3)) << 3);
    gA[q] = Ap + (long)(bm + r) * lda + sw;
    gB[q] = Bp + (long)(bn + r) * ldb + sw;
    lchunk[q] = (wave * 2 + q) * 512;
  }

  f32x4 acc[4][4];
#pragma unroll
  for (int i = 0; i < 4; ++i)
#pragma unroll
    for (int j = 0; j < 4; ++j) acc[i][j] = (f32x4){0.f, 0.f, 0.f, 0.f};

  const int x0 = (l15 >> 1) & 3;
  const int nk = K >> 5;

#pragma unroll
  for (int q = 0; q < 2; ++q) {
    async16(&lds[0][0][lchunk[q]], gA[q]);
    async16(&lds[0][1][lchunk[q]], gB[q]);
  }
#pragma unroll
  for (int q = 0; q < 2; ++q) {
    async16(&lds[1][0][lchunk[q]], gA[q] + 32);
    async16(&lds[1][1][lchunk[q]], gB[q] + 32);
  }

  int rb_ = 0, sb_ = 2;
  for (int k = 0; k < nk; ++k) {
    if (k + 2 < nk) {
      int k0 = (k + 2) << 5;
#pragma unroll
      for (int q = 0; q < 2; ++q) {
        async16(&lds[sb_][0][lchunk[q]], gA[q] + k0);
        async16(&lds[sb_][1][lchunk[q]], gB[q] + k0);
      }
    }
    if (k + 2 < nk)      asm volatile("s_waitcnt vmcnt(8)" ::: "memory");
    else if (k + 1 < nk) asm volatile("s_waitcnt vmcnt(4)" ::: "memory");
    else                 asm volatile("s_waitcnt vmcnt(0)" ::: "memory");
    __builtin_amdgcn_s_barrier();
    asm volatile("" ::: "memory");

    short8 aF[4], bF[4];
#pragma unroll
    for (int t = 0; t < 4; ++t) {
      int ra = (wm + t * 16 + l15) << 5;
      aF[t] = *(const short8*)&lds[rb_][0][ra + ((quad ^ x0) << 3)];
      int rbo = (wn + t * 16 + l15) << 5;
      bF[t] = *(const short8*)&lds[rb_][1][rbo + ((quad ^ x0) << 3)];
    }
#pragma unroll
    for (int i = 0; i < 4; ++i)
#pragma unroll
      for (int j = 0; j < 4; ++j)
        acc[i][j] = __builtin_amdgcn_mfma_f32_16x16x32_bf16(aF[i], bF[j], acc[i][j], 0, 0, 0);

    asm volatile("s_waitcnt lgkmcnt(0)" ::: "memory");
    __builtin_amdgcn_s_barrier();
    asm volatile("" ::: "memory");
    rb_ = (rb_ == 2) ? 0 : rb_ + 1;
    sb_ = (sb_ == 2) ? 0 : sb_ + 1;
  }
  __syncthreads();

  ushortT* ct = &lds[0][0][0];
  const float* bz = bp + (long)zz * bstride;
#pragma unroll
  for (int j = 0; j < 4; ++j) {
    int tcol = wn + j * 16 + l15;
    float cbv = (bmode == 1) ? bz[bn + tcol] : 0.0f;
#pragma unroll
    for (int i = 0; i < 4; ++i) {
      int row0 = wm + i * 16 + (quad << 2);
#pragma unroll
      for (int r = 0; r < 4; ++r) {
        int row = row0 + r;
        float bv = (bmode == 2) ? bz[bm + row] : cbv;
        float v = acc[i][j][r] * scale + bv;
        if (EMODE == 1) v = gelu_f(v);
        ct[(row << 7) + tcol] = f2b(v);
      }
    }
  }
  __syncthreads();

  if (EMODE == 2) {
    const bool isq = (bn < 512);
    ushortT* dbase = isq ? C : C2;
    const int cbase = isq ? bn : bn - 512;
#pragma unroll
    for (int it = 0; it < 8; ++it) {
      int trow = it * 16 + (tid >> 4);
      int tcol = (tid & 15) << 3;
      uint4 u = *(const uint4*)&ct[(trow << 7) + tcol];
      int grow = bm + trow;
      int pos = grow & 1023;
      int pair0 = (cbase + tcol) >> 1;
      const float2* tp = &tab[(pos << 8) + pair0];
      unsigned w[4] = {u.x, u.y, u.z, u.w};
      uint4 o;
      unsigned* op = (unsigned*)&o;
#pragma unroll
      for (int p = 0; p < 4; ++p) {
        float2 sc = tp[p];
        float x1 = b2f((ushortT)(w[p] & 0xFFFFu));
        float x2 = b2f((ushortT)(w[p] >> 16));
        float o1 = x1 * sc.y - x2 * sc.x;
        float o2 = x1 * sc.x + x2 * sc.y;
        op[p] = (unsigned)f2b(o1) | ((unsigned)f2b(o2) << 16);
      }
      *(uint4*)&dbase[coff + (long)grow * 512 + cbase + tcol] = o;
    }
  } else {
#pragma unroll
    for (int it = 0; it < 8; ++it) {
      int trow = it * 16 + (tid >> 4);
      int tcol = (tid & 15) << 3;
      *(uint4*)&C[coff + (long)(bm + trow) * ldc + bn + tcol] =
          *(const uint4*)&ct[(trow << 7) + tcol];
    }
  }
}

// ---------- batched tiled transpose (z,R,C)->(z,C,R) bf16->bf16, optional gather ----------
__global__ void btrans(const ushortT* __restrict__ in, ushortT* __restrict__ out,
                       int R, int C, long ibs, const int* __restrict__ gather) {
  __shared__ float tile[32][33];
  int z = blockIdx.z;
  long ib = (long)(gather ? gather[z] : z) * ibs;
  long ob = (long)z * (long)R * C;
  int c0 = blockIdx.x << 5, r0 = blockIdx.y << 5;
  int tx = threadIdx.x, ty = threadIdx.y;
#pragma unroll
  for (int dy = 0; dy < 32; dy += 8)
    tile[ty + dy][tx] = b2f(in[ib + (long)(r0 + ty + dy) * C + c0 + tx]);
  __syncthreads();
#pragma unroll
  for (int dy = 0; dy < 32; dy += 8)
    out[ob + (long)(c0 + ty + dy) * R + r0 + tx] = f2b(tile[tx][ty + dy]);
}

// ---------- all 26 weight transposes in one dispatch: f32 (512,512) -> bf16 W^T ----------
struct WSrc { const float* p[8]; int c[8]; };
__global__ void wtrans_all(WSrc ws, ushortT* __restrict__ out) {
  __shared__ float tile[32][33];
  int z = blockIdx.z;
  int g = 0, base = 0;
  while (z - base >= ws.c[g]) { base += ws.c[g]; ++g; }
  const float* src = ws.p[g] + (size_t)(z - base) * 262144;
  ushortT* dst = out + (size_t)z * 262144;
  int c0 = blockIdx.x << 5, r0 = blockIdx.y << 5;
  int tx = threadIdx.x, ty = threadIdx.y;
#pragma unroll
  for (int dy = 0; dy < 32; dy += 8)
    tile[ty + dy][tx] = src[(long)(r0 + ty + dy) * 512 + c0 + tx];
  __syncthreads();
#pragma unroll
  for (int dy = 0; dy < 32; dy += 8)
    dst[(long)(c0 + ty + dy) * 512 + r0 + tx] = f2b(tile[tx][ty + dy]);
}

// ---------- fused setup: softmax biases, rope table, f32->bf16 convs, zero vec ----------
__device__ __forceinline__ void conv4(const float4* in, uint2* out, long i) {
  float4 v = in[i];
  uint2 r;
  r.x = (unsigned)f2b(v.x) | ((unsigned)f2b(v.y) << 16);
  r.y = (unsigned)f2b(v.z) | ((unsigned)f2b(v.w) << 16);
  out[i] = r;
}
__global__ __launch_bounds__(256)
void setup_k(const float* __restrict__ rpw, const float* __restrict__ rpr,
             const float* __restrict__ questions, const float* __restrict__ raw,
             const float* __restrict__ pd,
             float* __restrict__ pbw, float* __restrict__ pbr, float2* __restrict__ tab,
             uint2* __restrict__ qsb, uint2* __restrict__ rab, uint2* __restrict__ pdb,
             float* __restrict__ zb) {
  int b = blockIdx.x, t = threadIdx.x;
  if (b < 32) { int i = b * 256 + t; float v = rpw[i]; pbw[i] = __logf(v); return; }
  b -= 32;
  if (b < 64) { int i = b * 256 + t; float v = rpr[i]; pbr[i] = __logf(v) - log1pf(-v); return; }
  b -= 64;
  if (b < 1024) {
    float inv = __expf(-(float)t * 0.035977892078032f);
    float s, c;
    sincosf((float)b * inv, &s, &c);
    tab[(b << 8) + t] = make_float2(s, c);
    return;
  }
  b -= 1024;
  if (b < 32) { conv4((const float4*)questions, qsb, (long)b * 256 + t); return; }
  b -= 32;
  if (b < 4096) { conv4((const float4*)raw, rab, (long)b * 256 + t); return; }
  b -= 4096;
  if (b < 8192) { conv4((const float4*)pd, pdb, (long)b * 256 + t); return; }
  b -= 8192;
  zb[b * 256 + t] = 0.0f;
}

// ---------- in-place softmax, L=1024, WAVE-PER-ROW (4 rows/block, 16 elem/lane) ----------
__global__ __launch_bounds__(256)
void softmax1024(ushortT* __restrict__ x) {
  int row = blockIdx.x * 4 + (threadIdx.x >> 6), lane = threadIdx.x & 63;
  ushortT* xr = x + (long)row * 1024;
  uint4 u0 = ((const uint4*)xr)[lane * 2];
  uint4 u1 = ((const uint4*)xr)[lane * 2 + 1];
  unsigned w[8] = {u0.x, u0.y, u0.z, u0.w, u1.x, u1.y, u1.z, u1.w};
  float t[16];
#pragma unroll
  for (int i = 0; i < 8; ++i) {
    t[2 * i]     = b2f((ushortT)(w[i] & 0xFFFFu));
    t[2 * i + 1] = b2f((ushortT)(w[i] >> 16));
  }
  float m = t[0];
#pragma unroll
  for (int i = 1; i < 16; ++i) m = fmaxf(m, t[i]);
  for (int o = 32; o; o >>= 1) m = fmaxf(m, __shfl_xor(m, o));
  float s = 0.f;
#pragma unroll
  for (int i = 0; i < 16; ++i) { t[i] = __expf(t[i] - m); s += t[i]; }
  for (int o = 32; o; o >>= 1) s += __shfl_xor(s, o);
  float inv = 1.0f / s;
#pragma unroll
  for (int i = 0; i < 8; ++i)
    w[i] = (unsigned)f2b(t[2 * i] * inv) | ((unsigned)f2b(t[2 * i + 1] * inv) << 16);
  uint4 o0; o0.x = w[0]; o0.y = w[1]; o0.z = w[2]; o0.w = w[3];
  uint4 o1; o1.x = w[4]; o1.y = w[5]; o1.z = w[6]; o1.w = w[7];
  ((uint4*)xr)[lane * 2]     = o0;
  ((uint4*)xr)[lane * 2 + 1] = o1;
}

// ---------- in-place softmax, L=64 (one wave per row; scale pre-folded) ----------
__global__ __launch_bounds__(256)
void softmax64(ushortT* __restrict__ x, int ldr) {
  int row = blockIdx.x * 4 + (threadIdx.x >> 6), lane = threadIdx.x & 63;
  ushortT* xr = x + (long)row * ldr;
  float t = b2f(xr[lane]);
  float m = t;
  for (int o = 32; o; o >>= 1) m = fmaxf(m, __shfl_xor(m, o));
  float e = __expf(t - m), s = e;
  for (int o = 32; o; o >>= 1) s += __shfl_xor(s, o);
  xr[lane] = f2b(e / s);
}

// ---------- fused residual + LayerNorm, WAVE-PER-ROW (4 rows/block, 8 elem/lane) ----------
__global__ __launch_bounds__(256)
void ln_k(const ushortT* __restrict__ src, const ushortT* __restrict__ res,
          const float* __restrict__ gamma, const float* __restrict__ beta,
          const float* __restrict__ gamma2, const float* __restrict__ beta2,
          int rsplit, ushortT* __restrict__ dst) {
  int row = blockIdx.x * 4 + (threadIdx.x >> 6), lane = threadIdx.x & 63;
  const float* gp = gamma; const float* bp = beta;
  if (row >= rsplit) { gp = gamma2; bp = beta2; }
  long off = (long)row * 512 + lane * 8;
  short8 sv = *(const short8*)&src[off];
  short8 rv = *(const short8*)&res[off];
  float a[8]; float s = 0.f, q = 0.f;
#pragma unroll
  for (int j = 0; j < 8; ++j) {
    a[j] = b2f((ushortT)sv[j]) + b2f((ushortT)rv[j]);
    s += a[j]; q += a[j] * a[j];
  }
  for (int o = 32; o; o >>= 1) { s += __shfl_xor(s, o); q += __shfl_xor(q, o); }
  float mean = s * (1.0f / 512.0f);
  float var = q * (1.0f / 512.0f) - mean * mean;
  float rstd = rsqrtf(fmaxf(var, 0.f) + 1e-5f);
  unsigned w[4];
#pragma unroll
  for (int j = 0; j < 4; ++j) {
    float v0 = (a[2 * j]     - mean) * rstd * gp[lane * 8 + 2 * j]     + bp[lane * 8 + 2 * j];
    float v1 = (a[2 * j + 1] - mean) * rstd * gp[lane * 8 + 2 * j + 1] + bp[lane * 8 + 2 * j + 1];
    w[j] = (unsigned)f2b(v0) | ((unsigned)f2b(v1) << 16);
  }
  uint4 o; o.x = w[0]; o.y = w[1]; o.z = w[2]; o.w = w[3];
  *(uint4*)&dst[off] = o;
}

// ---------- v = raw * sigmoid(fi @ W_ig + b_ig), WAVE-PER-ROW ----------
__global__ __launch_bounds__(256)
void gatev_k(const ushortT* __restrict__ fi, const float* __restrict__ raw,
             const float* __restrict__ wig, const float* __restrict__ big,
             ushortT* __restrict__ vout) {
  int row = blockIdx.x * 4 + (threadIdx.x >> 6), lane = threadIdx.x & 63;
  long off = (long)row * 512 + lane * 8;
  short8 fv = *(const short8*)&fi[off];
  float d = 0.f;
#pragma unroll
  for (int j = 0; j < 8; ++j) d += b2f((ushortT)fv[j]) * wig[lane * 8 + j];
  for (int o = 32; o; o >>= 1) d += __shfl_xor(d, o);
  float g = 1.0f / (1.0f + __expf(-(d + big[0])));
  float4 r0 = *(const float4*)&raw[off];
  float4 r1 = *(const float4*)&raw[off + 4];
  unsigned w[4];
  w[0] = (unsigned)f2b(r0.x * g) | ((unsigned)f2b(r0.y * g) << 16);
  w[1] = (unsigned)f2b(r0.z * g) | ((unsigned)f2b(r0.w * g) << 16);
  w[2] = (unsigned)f2b(r1.x * g) | ((unsigned)f2b(r1.y * g) << 16);
  w[3] = (unsigned)f2b(r1.z * g) | ((unsigned)f2b(r1.w * g) << 16);
  uint4 o; o.x = w[0]; o.y = w[1]; o.z = w[2]; o.w = w[3];
  *(uint4*)&vout[off] = o;
}

// ---------- final gating + output write (f32 out), WAVE-PER-ROW ----------
__global__ __launch_bounds__(256)
void final_k(const ushortT* __restrict__ fu, const ushortT* __restrict__ A2,
             const float* __restrict__ pd, const float* __restrict__ wu1,
             const float* __restrict__ wu2, const float* __restrict__ bu1,
             const float* __restrict__ bu2, const float* __restrict__ b1p,
             float* __restrict__ outx, float* __restrict__ outg) {
  int row = blockIdx.x * 4 + (threadIdx.x >> 6), lane = threadIdx.x & 63;
  long off = (long)row * 512 + lane * 8;
  short8 fv = *(const short8*)&fu[off];
  short8 av = *(const short8*)&A2[off];
  float a2[8]; float d1 = 0.f, d2 = 0.f;
#pragma unroll
  for (int j = 0; j < 8; ++j) {
    a2[j] = b2f((ushortT)av[j]);
    d1 += b2f((ushortT)fv[j]) * wu1[lane * 8 + j];
    d2 += a2[j] * wu2[lane * 8 + j];
  }
  for (int o = 32; o; o >>= 1) { d1 += __shfl_xor(d1, o); d2 += __shfl_xor(d2, o); }
  float g = 1.0f / (1.0f + __expf(-(d1 + d2 + bu1[0] + bu2[0] + b1p[0] - 4.0f)));
  float4 p0 = *(const float4*)&pd[off];
  float4 p1 = *(const float4*)&pd[off + 4];
  float4 o0, o1;
  o0.x = p0.x * (1.0f - g) + a2[0] * g;
  o0.y = p0.y * (1.0f - g) + a2[1] * g;
  o0.z = p0.z * (1.0f - g) + a2[2] * g;
  o0.w = p0.w * (1.0f - g) + a2[3] * g;
  o1.x = p1.x * (1.0f - g) + a2[4] * g;
  o1.y = p1.y * (1.0f - g) + a2[5] * g;
  o1.z = p1.z * (1.0f - g) + a2[6] * g;
  o1.w = p1.w * (1.0f - g) + a2[7] * g;
  *(float4*)&outx[off]     = o0;
  *(float4*)&outx[off + 4] = o1;
  if (lane == 0) outg[row] = g;
}

// ================= host orchestration =================
extern "C" void kernel_launch(void* const* d_in, const int* in_sizes, int n_in,
                              void* d_out, int out_size, void* d_ws, size_t ws_size,
                              hipStream_t stream)
{
  const float* raw_emb = (const float*)d_in[0];
  const float* rpw     = (const float*)d_in[1];
  const float* post_dec= (const float*)d_in[2];
  const float* rpr     = (const float*)d_in[3];
  const float* questions=(const float*)d_in[4];
  const float* W_k  = (const float*)d_in[5];
  const float* W_ig = (const float*)d_in[6];
  const float* b_ig = (const float*)d_in[7];
  const float* W_u1 = (const float*)d_in[8];
  const float* b_u1 = (const float*)d_in[9];
  const float* W_u2 = (const float*)d_in[10];
  const float* b_u2 = (const float*)d_in[11];
  const float* b1   = (const float*)d_in[12];
  const float* W_ok = (const float*)d_in[13];
  const float* b_ok = (const float*)d_in[14];
  const float* ew_qkv = (const float*)d_in[15];
  const float* ew_bqkv= (const float*)d_in[16];
  const float* ew_wo  = (const float*)d_in[17];
  const float* ew_bo  = (const float*)d_in[18];
  const float* ew_ln  = (const float*)d_in[19];
  const float* ew_wff = (const float*)d_in[20];
  const float* ew_bff = (const float*)d_in[21];
  const float* er_qkv = (const float*)d_in[22];
  const float* er_bqkv= (const float*)d_in[23];
  const float* er_wo  = (const float*)d_in[24];
  const float* er_bo  = (const float*)d_in[25];
  const float* er_ln  = (const float*)d_in[26];
  const float* er_wff = (const float*)d_in[27];
  const float* er_bff = (const float*)d_in[28];
  const int* lookup   = (const int*)d_in[29];

  const size_t MAT = 512ull * 512ull;
  const long SD = 1024l * 512;
  const long SZ = 8192l * 512;
  const int BIGZ = 1 << 28;
  char* wsb = (char*)d_ws;
  size_t off = 0;
  auto alloc = [&](size_t b) { char* p = wsb + off; off = (off + b + 255) & ~(size_t)255; return p; };

  ushortT* WT  = (ushortT*)alloc(26 * MAT * 2);
  ushortT* RAB = (ushortT*)alloc(8192ull * 512 * 2);
  ushortT* PDB = (ushortT*)alloc(16384ull * 512 * 2);
  ushortT* XC  = (ushortT*)alloc(24576ull * 512 * 2);
  ushortT* B1  = (ushortT*)alloc(24576ull * 512 * 2);
  ushortT* SC  = (ushortT*)alloc(24ull * 1024 * 1024 * 2);
  ushortT* QB  = (ushortT*)alloc(24576ull * 512 * 2);
  ushortT* KB  = (ushortT*)alloc(24576ull * 512 * 2);
  ushortT* VT  = (ushortT*)alloc(24ull * 512 * 1024 * 2);
  ushortT* KD2 = (ushortT*)alloc(24576ull * 512 * 2);
  ushortT* QSB = (ushortT*)alloc(128ull * 512 * 2);
  ushortT* SC2 = (ushortT*)alloc(16384ull * 128 * 2);
  ushortT* A1S = (ushortT*)alloc(8ull * 128 * 512 * 2);
  ushortT* SAT = (ushortT*)alloc(16ull * 512 * 64 * 2);
  float*   PBW = (float*)alloc(8192 * 4);
  float*   PBR = (float*)alloc(16384 * 4);
  float2*  TAB = (float2*)alloc(1024 * 256 * 8);
  float*   ZB  = (float*)alloc(512 * 4);

  auto gemm = [&](int emode, const ushortT* A, const ushortT* Bt,
                  const ushortT* A2p, const ushortT* Bt2p,
                  ushortT* C, ushortT* C2,
                  const float* bias, const float* bias2, int zsplit,
                  int bmode, float scale, long bstride,
                  int M, int N, int K, int lda, int ldb, int ldc,
                  int Z, long sA, long sB, long sC) {
    dim3 g(N / 128, M / 128, Z);
    if (emode == 0)
      gemm_f<0><<<g, dim3(256), 0, stream>>>(A, Bt, A2p, Bt2p, C, nullptr, bias, bias2,
                                             zsplit, bmode, scale, bstride,
                                             K, lda, ldb, ldc, sA, sB, sC, TAB);
    else if (emode == 1)
      gemm_f<1><<<g, dim3(256), 0, stream>>>(A, Bt, A2p, Bt2p, C, nullptr, bias, bias2,
                                             zsplit, bmode, scale, bstride,
                                             K, lda, ldb, ldc, sA, sB, sC, TAB);
    else
      gemm_f<2><<<g, dim3(256), 0, stream>>>(A, Bt, A2p, Bt2p, C, C2, bias, bias2,
                                             zsplit, bmode, scale, bstride,
                                             K, lda, ldb, ldc, sA, sB, sC, TAB);
  };

  const float isc512 = 0.044194173824159216f; // 1/sqrt(512)

  // 0. setup
  WSrc wsrc;
  wsrc.p[0] = W_k;    wsrc.c[0] = 1;
  wsrc.p[1] = W_ok;   wsrc.c[1] = 1;
  wsrc.p[2] = ew_qkv; wsrc.c[2] = 6;
  wsrc.p[3] = ew_wo;  wsrc.c[3] = 2;
  wsrc.p[4] = ew_wff; wsrc.c[4] = 4;
  wsrc.p[5] = er_qkv; wsrc.c[5] = 6;
  wsrc.p[6] = er_wo;  wsrc.c[6] = 2;
  wsrc.p[7] = er_wff; wsrc.c[7] = 4;
  wtrans_all<<<dim3(16, 16, 26), dim3(32, 8), 0, stream>>>(wsrc, WT);
  setup_k<<<13442, 256, 0, stream>>>(rpw, rpr, questions, raw_emb, post_dec,
                                     PBW, PBR, TAB, (uint2*)QSB, (uint2*)RAB, (uint2*)PDB, ZB);

  // 1. merged k_docs + k2
  gemm(0, RAB, WT + 0 * MAT, RAB + SZ, WT + 1 * MAT, KD2, nullptr,
       ZB, b_ok, 1, 1, 1.0f, 0,
       8192, 512, 512, 512, 512, 512, 3, SZ, 0, SZ);

  // 2. merged dual-encoder sweep
  for (int l = 0; l < 2; ++l) {
    const ushortT* xs = (l == 0) ? RAB : XC;
    const ushortT* WqkW = WT + (size_t)(2 + l * 3) * MAT;
    const ushortT* WqkR = WT + (size_t)(14 + l * 3) * MAT;
    const ushortT* WvW  = WT + (size_t)(4 + l * 3) * MAT;
    const ushortT* WvR  = WT + (size_t)(16 + l * 3) * MAT;
    const ushortT* WoW  = WT + (size_t)(8 + l) * MAT;
    const ushortT* WoR  = WT + (size_t)(20 + l) * MAT;
    const ushortT* Wf0W = WT + (size_t)(10 + l * 2) * MAT;
    const ushortT* Wf0R = WT + (size_t)(22 + l * 2) * MAT;
    const ushortT* Wf1W = WT + (size_t)(11 + l * 2) * MAT;
    const ushortT* Wf1R = WT + (size_t)(23 + l * 2) * MAT;

    gemm(2, xs, WqkW, xs + SZ, WqkR, QB, KB,
         ew_bqkv + (l * 3) * 512, er_bqkv + (l * 3) * 512, 1,
         1, 1.0f, 0,
         8192, 1024, 512, 512, 512, 512, 3, SZ, 0, SZ);
    gemm(0, WvW, xs, WvR, xs + 8 * SD, VT, nullptr,
         ew_bqkv + (l * 3 + 2) * 512, er_bqkv + (l * 3 + 2) * 512, 8,
         2, 1.0f, 0,
         512, 1024, 512, 512, 512, 1024, 24, 0, SD, SD);
    gemm(0, QB, KB, QB, KB, SC, nullptr,
         PBW, PBW, BIGZ, 1, isc512, 1024,
         1024, 1024, 512, 512, 512, 1024, 24, SD, SD, 1024l * 1024);
    softmax1024<<<6144, 256, 0, stream>>>(SC);
    gemm(0, SC, VT, SC, VT, QB, nullptr,
         nullptr, nullptr, BIGZ, 0, 1.0f, 0,
         1024, 512, 1024, 1024, 1024, 512, 24, 1024l * 1024, SD, SD);
    gemm(0, QB, WoW, QB + SZ, WoR, B1, nullptr,
         ew_bo + l * 512, er_bo + l * 512, 1, 1, 1.0f, 0,
         8192, 512, 512, 512, 512, 512, 3, SZ, 0, SZ);
    ln_k<<<6144, 256, 0, stream>>>(xs, B1,
         ew_ln + (l * 4 + 0) * 512, ew_ln + (l * 4 + 1) * 512,
         er_ln + (l * 4 + 0) * 512, er_ln + (l * 4 + 1) * 512, 8192, XC);
    gemm(1, XC, Wf0W, XC + SZ, Wf0R, KB, nullptr,
         ew_bff + (l * 2) * 512, er_bff + (l * 2) * 512, 1, 1, 1.0f, 0,
         8192, 512, 512, 512, 512, 512, 3, SZ, 0, SZ);
    gemm(0, KB, Wf1W, KB + SZ, Wf1R, B1, nullptr,
         ew_bff + (l * 2 + 1) * 512, er_bff + (l * 2 + 1) * 512, 1, 1, 1.0f, 0,
         8192, 512, 512, 512, 512, 512, 3, SZ, 0, SZ);
    ln_k<<<6144, 256, 0, stream>>>(XC, B1,
         ew_ln + (l * 4 + 2) * 512, ew_ln + (l * 4 + 3) * 512,
         er_ln + (l * 4 + 2) * 512, er_ln + (l * 4 + 3) * 512, 8192, XC);
  }

  // 3. v_gate, A1s
  gatev_k<<<2048, 256, 0, stream>>>(XC, raw_emb, W_ig, b_ig, B1);
  btrans<<<dim3(16, 32, 8), dim3(32, 8), 0, stream>>>(B1, VT, 1024, 512, SD, nullptr);
  gemm(0, QSB, KD2, QSB, KD2, SC2, nullptr,
       PBW, PBW, BIGZ, 1, isc512, 1024,
       128, 1024, 512, 512, 512, 1024, 8, 0, SD, 128l * 1024);
  softmax1024<<<256, 256, 0, stream>>>(SC2);
  gemm(0, SC2, VT, SC2, VT, A1S, nullptr,
       nullptr, nullptr, BIGZ, 0, 1.0f, 0,
       128, 512, 1024, 1024, 1024, 512, 8, 128l * 1024, SD, 128l * 512);

  // 4. a2, A2
  gemm(0, KD2 + SZ, QSB, KD2 + SZ, QSB, SC2, nullptr,
       nullptr, nullptr, BIGZ, 0, 0.125f, 0,
       16384, 128, 512, 512, 512, 128, 1, 0, 0, 0);
  softmax64<<<4096, 256, 0, stream>>>(SC2, 128);
  btrans<<<dim3(16, 2, 16), dim3(32, 8), 0, stream>>>(A1S, SAT, 64, 512, 128 * 512, lookup);
  gemm(0, SC2, SAT, SC2, SAT, QB, nullptr,
       nullptr, nullptr, BIGZ, 0, 1.0f, 0,
       1024, 512, 64, 128, 64, 512, 16, 1024l * 128, 512l * 64, SD);

  // 5. final gate + output
  float* outp = (float*)d_out;
  final_k<<<4096, 256, 0, stream>>>(XC + SZ, QB, post_dec, W_u1, W_u2, b_u1, b_u2, b1,
                                    outp, outp + 8388608);
}